// Round 1
// baseline (899.535 us; speedup 1.0000x reference)
//
#include <hip/hip_runtime.h>
#include <math.h>

// Problem constants
#define Bn 2
#define Vn 6
#define Cn 96
#define Dn 48
#define Hn 48
#define Wn 48
#define THn 96
#define TWn 96
#define EPSf 1e-5f

// ---------------------------------------------------------------------------
// K1: rotated projection -> feat2d, layout (v,b,y,x,c) with c fastest.
// iy == y exactly (rotation about Y), so sample is bilinear in (x,z),
// averaged over 48 z-steps. Lanes = consecutive c -> coalesced tap loads.
// ---------------------------------------------------------------------------
__global__ __launch_bounds__(256) void k_feat(const float* __restrict__ tokens,
                                              const float* __restrict__ angles,
                                              float* __restrict__ feat) {
    int idx = blockIdx.x * 256 + threadIdx.x;
    const int total = Vn * Bn * Hn * Wn * Cn;  // 2,654,208
    if (idx >= total) return;
    int c = idx % Cn;
    int r = idx / Cn;
    int x = r % Wn; r /= Wn;
    int y = r % Hn; r /= Hn;
    int b = r % Bn;
    int v = r / Bn;

    float th = angles[v];
    float ct = cosf(th), st = sinf(th);
    float X = (x + 0.5f) * (2.0f / 48.0f) - 1.0f;
    const float* tb = tokens + (size_t)b * (Dn * Hn * Wn) * Cn + c;

    float acc = 0.0f;
    for (int z = 0; z < Dn; ++z) {
        float Zc = (z + 0.5f) * (2.0f / 48.0f) - 1.0f;
        float gx =  ct * X + st * Zc;
        float gz = -st * X + ct * Zc;
        float ix = ((gx + 1.0f) * 48.0f - 1.0f) * 0.5f;
        float iz = ((gz + 1.0f) * 48.0f - 1.0f) * 0.5f;
        float x0f = floorf(ix), z0f = floorf(iz);
        float tx = ix - x0f, tz = iz - z0f;
        int x0 = (int)x0f, z0 = (int)z0f;
        float wx[2] = {1.0f - tx, tx};
        float wz[2] = {1.0f - tz, tz};
#pragma unroll
        for (int dz = 0; dz < 2; ++dz) {
            int zc = z0 + dz;
            bool zin = (zc >= 0) && (zc < Dn);
            int zi = min(max(zc, 0), Dn - 1);
#pragma unroll
            for (int dx = 0; dx < 2; ++dx) {
                int xc = x0 + dx;
                bool xin = (xc >= 0) && (xc < Wn);
                int xi = min(max(xc, 0), Wn - 1);
                float w = wx[dx] * wz[dz] * ((zin && xin) ? 1.0f : 0.0f);
                float val = tb[(size_t)((zi * Hn + y) * Wn + xi) * Cn];
                acc += w * val;
            }
        }
    }
    feat[idx] = acc * (1.0f / 48.0f);
}

// ---------------------------------------------------------------------------
// K2: fused (bilinear resize 48->96) + conv1 3x3 SAME.
// Block = (v,b,y-row). LDS stages resized rows y-1..y+1 for a 32-ci chunk,
// computing the resize on the fly from feat (4 taps, amortized over 96 co).
// Thread tiling: 12 co x 3 x per thread (36 fp32 acc).
// Output layout: (v,b,co,y,x).
// ---------------------------------------------------------------------------
#define CI_CHUNK 32
__global__ __launch_bounds__(256) void k_conv1(const float* __restrict__ feat,
                                               const float* __restrict__ w1,
                                               float* __restrict__ out) {
    int blk = blockIdx.x;          // vb*96 + y
    int y  = blk % THn;
    int vb = blk / THn;            // 0..11

    __shared__ float R[CI_CHUNK][3][98];   // [ci][row y-1..y+1][x=-1..96]

    int t = threadIdx.x;
    int xg  = t & 31;   // 0..31  (x = xg, xg+32, xg+64)
    int cog = t >> 5;   // 0..7   (co = cog + 8j, j=0..11)

    float acc[12][3];
#pragma unroll
    for (int j = 0; j < 12; ++j)
#pragma unroll
        for (int k = 0; k < 3; ++k) acc[j][k] = 0.0f;

    const float* fbase = feat + (size_t)vb * (Hn * Wn * Cn);

    for (int cc = 0; cc < Cn; cc += CI_CHUNK) {
        __syncthreads();
        // ---- stage: resized values for rows y-1..y+1, x=-1..96, ci chunk
        for (int e = t; e < CI_CHUNK * 3 * 98; e += 256) {
            int ci  = e & (CI_CHUNK - 1);
            int rem = e >> 5;
            int xx  = rem % 98;
            int rr  = rem / 98;        // 0..2
            int yr  = y + rr - 1;
            int xp  = xx - 1;
            float val = 0.0f;
            if (yr >= 0 && yr < THn && xp >= 0 && xp < TWn) {
                float sy = fmaxf(0.5f * (yr + 0.5f) - 0.5f, 0.0f);
                int y0 = min((int)floorf(sy), Hn - 1);
                int y1 = min(y0 + 1, Hn - 1);
                float ty = sy - (float)y0;
                float sx = fmaxf(0.5f * (xp + 0.5f) - 0.5f, 0.0f);
                int x0 = min((int)floorf(sx), Wn - 1);
                int x1 = min(x0 + 1, Wn - 1);
                float tx = sx - (float)x0;
                const float* fp = fbase + (cc + ci);
                float f00 = fp[(size_t)(y0 * Wn + x0) * Cn];
                float f01 = fp[(size_t)(y0 * Wn + x1) * Cn];
                float f10 = fp[(size_t)(y1 * Wn + x0) * Cn];
                float f11 = fp[(size_t)(y1 * Wn + x1) * Cn];
                val = (1.0f - ty) * ((1.0f - tx) * f00 + tx * f01)
                    +          ty * ((1.0f - tx) * f10 + tx * f11);
            }
            R[ci][rr][xx] = val;
        }
        __syncthreads();
        // ---- compute
        for (int ci = 0; ci < CI_CHUNK; ++ci) {
            int cig = cc + ci;
#pragma unroll
            for (int dy = 0; dy < 3; ++dy) {
#pragma unroll
                for (int dx = 0; dx < 3; ++dx) {
                    float in0 = R[ci][dy][xg + dx];
                    float in1 = R[ci][dy][xg + 32 + dx];
                    float in2 = R[ci][dy][xg + 64 + dx];
                    int wbase = (cig * 9) + dy * 3 + dx;
#pragma unroll
                    for (int j = 0; j < 12; ++j) {
                        int co = cog + 8 * j;
                        float w = w1[(size_t)co * (Cn * 9) + wbase];
                        acc[j][0] += w * in0;
                        acc[j][1] += w * in1;
                        acc[j][2] += w * in2;
                    }
                }
            }
        }
    }

    // ---- write (v,b,co,y,x)
#pragma unroll
    for (int j = 0; j < 12; ++j) {
        int co = cog + 8 * j;
        size_t base = ((size_t)(vb * Cn + co) * THn + y) * TWn;
#pragma unroll
        for (int k = 0; k < 3; ++k)
            out[base + xg + 32 * k] = acc[j][k];
    }
}

// ---------------------------------------------------------------------------
// K3: BN stats per (v,c) over (b, y, x) -> mu, rstd
// ---------------------------------------------------------------------------
__global__ __launch_bounds__(256) void k_stats(const float* __restrict__ co1,
                                               float* __restrict__ mu,
                                               float* __restrict__ rstd) {
    int vc = blockIdx.x;          // v*96 + c
    int v = vc / Cn, c = vc % Cn;
    const int HW = THn * TWn;     // 9216
    const float* p0 = co1 + ((size_t)(v * Bn + 0) * Cn + c) * HW;
    const float* p1 = co1 + ((size_t)(v * Bn + 1) * Cn + c) * HW;

    float s = 0.0f, ss = 0.0f;
    for (int i = threadIdx.x; i < HW; i += 256) {
        float a = p0[i], b = p1[i];
        s  += a + b;
        ss += a * a + b * b;
    }
#pragma unroll
    for (int off = 32; off > 0; off >>= 1) {
        s  += __shfl_down(s, off);
        ss += __shfl_down(ss, off);
    }
    __shared__ float shs[4], shss[4];
    int wid = threadIdx.x >> 6;
    if ((threadIdx.x & 63) == 0) { shs[wid] = s; shss[wid] = ss; }
    __syncthreads();
    if (threadIdx.x == 0) {
        float S  = shs[0] + shs[1] + shs[2] + shs[3];
        float SS = shss[0] + shss[1] + shss[2] + shss[3];
        const float invN = 1.0f / (Bn * HW);
        float m = S * invN;
        float var = fmaxf(SS * invN - m * m, 0.0f);
        mu[vc] = m;
        rstd[vc] = rsqrtf(var + EPSf);
    }
}

// ---------------------------------------------------------------------------
// K4: batchnorm affine + exact GELU, in place on conv1 output
// ---------------------------------------------------------------------------
__global__ __launch_bounds__(256) void k_bngelu(float* __restrict__ co1,
                                                const float* __restrict__ mu,
                                                const float* __restrict__ rstd,
                                                const float* __restrict__ gamma,
                                                const float* __restrict__ beta) {
    int idx = blockIdx.x * 256 + threadIdx.x;
    const int total = Vn * Bn * Cn * THn * TWn;  // 10,616,832
    if (idx >= total) return;
    int r = idx / (THn * TWn);
    int c = r % Cn;
    r /= Cn;              // vb
    int v = r / Bn;
    float m  = mu[v * Cn + c];
    float rs = rstd[v * Cn + c];
    float xv = co1[idx];
    float yv = (xv - m) * rs * gamma[c] + beta[c];
    float g = 0.5f * yv * (1.0f + erff(yv * 0.70710678118654752f));
    co1[idx] = g;
}

// ---------------------------------------------------------------------------
// K5: conv2 1x1 + bias, with output transpose to (b,v,co,y,x)
// Block = (v,b,y-row); LDS stages 32-ci x 96-x activation chunk.
// ---------------------------------------------------------------------------
__global__ __launch_bounds__(256) void k_conv2(const float* __restrict__ g,
                                               const float* __restrict__ w2,
                                               const float* __restrict__ b2,
                                               float* __restrict__ out) {
    int blk = blockIdx.x;         // vb*96 + y
    int y  = blk % THn;
    int vb = blk / THn;
    int v = vb >> 1, b = vb & 1;

    __shared__ float G[32][96];
    int t = threadIdx.x;
    int xg  = t & 31;
    int cog = t >> 5;

    float acc[12][3];
#pragma unroll
    for (int j = 0; j < 12; ++j)
#pragma unroll
        for (int k = 0; k < 3; ++k) acc[j][k] = 0.0f;

    const int HW = THn * TWn;
    const float* gb = g + (size_t)vb * Cn * HW + (size_t)y * TWn;

    for (int cc = 0; cc < Cn; cc += 32) {
        __syncthreads();
        for (int e = t; e < 32 * 96; e += 256) {
            int ci = e / 96;
            int x  = e % 96;
            G[ci][x] = gb[(size_t)(cc + ci) * HW + x];
        }
        __syncthreads();
        for (int ci = 0; ci < 32; ++ci) {
            float in0 = G[ci][xg];
            float in1 = G[ci][xg + 32];
            float in2 = G[ci][xg + 64];
            int cig = cc + ci;
#pragma unroll
            for (int j = 0; j < 12; ++j) {
                float w = w2[(size_t)(cog + 8 * j) * Cn + cig];
                acc[j][0] += w * in0;
                acc[j][1] += w * in1;
                acc[j][2] += w * in2;
            }
        }
    }

#pragma unroll
    for (int j = 0; j < 12; ++j) {
        int co = cog + 8 * j;
        float bias = b2[co];
        size_t base = (((size_t)(b * Vn + v) * Cn + co) * THn + y) * TWn;
#pragma unroll
        for (int k = 0; k < 3; ++k)
            out[base + xg + 32 * k] = acc[j][k] + bias;
    }
}

// ---------------------------------------------------------------------------
extern "C" void kernel_launch(void* const* d_in, const int* in_sizes, int n_in,
                              void* d_out, int out_size, void* d_ws, size_t ws_size,
                              hipStream_t stream) {
    const float* tokens = (const float*)d_in[0];  // (2, 110592, 96)
    const float* angles = (const float*)d_in[1];  // (6,)
    const float* w1     = (const float*)d_in[2];  // (96,96,3,3)
    const float* gamma  = (const float*)d_in[3];  // (96,)
    const float* beta   = (const float*)d_in[4];  // (96,)
    const float* w2     = (const float*)d_in[5];  // (96,96,1,1)
    const float* b2     = (const float*)d_in[6];  // (96,)
    float* out = (float*)d_out;                   // (2,6,96,96,96)

    // workspace layout (bytes):
    //   feat:    V*B*48*48*96 fp32 = 10,616,832 B   @ 0
    //   conv1out:V*B*96*96*96 fp32 = 42,467,328 B   @ 10,616,832
    //   mu/rstd: 576 + 576 fp32                     @ 53,084,160
    char* ws = (char*)d_ws;
    float* feat  = (float*)(ws);
    float* co1   = (float*)(ws + 10616832);
    float* mu    = (float*)(ws + 53084160);
    float* rstd  = mu + Vn * Cn;

    const int featN = Vn * Bn * Hn * Wn * Cn;        // 2,654,208
    const int postN = Vn * Bn * Cn * THn * TWn;      // 10,616,832

    k_feat<<<(featN + 255) / 256, 256, 0, stream>>>(tokens, angles, feat);
    k_conv1<<<Vn * Bn * THn, 256, 0, stream>>>(feat, w1, co1);
    k_stats<<<Vn * Cn, 256, 0, stream>>>(co1, mu, rstd);
    k_bngelu<<<(postN + 255) / 256, 256, 0, stream>>>(co1, mu, rstd, gamma, beta);
    k_conv2<<<Vn * Bn * THn, 256, 0, stream>>>(co1, w2, b2, out);
}

// Round 2
// 660.861 us; speedup vs baseline: 1.3612x; 1.3612x over previous
//
#include <hip/hip_runtime.h>
#include <math.h>

// Problem constants
#define Bn 2
#define Vn 6
#define Cn 96
#define Dn 48
#define Hn 48
#define Wn 48
#define THn 96
#define TWn 96
#define EPSf 1e-5f

typedef __attribute__((ext_vector_type(8))) short s8v;   // 8 bf16 (4 VGPRs)
typedef __attribute__((ext_vector_type(4))) float f4v;   // MFMA acc

__device__ __forceinline__ unsigned short f2bf(float f) {
    unsigned int u = __builtin_bit_cast(unsigned int, f);
    u += 0x7FFFu + ((u >> 16) & 1u);          // RNE
    return (unsigned short)(u >> 16);
}
__device__ __forceinline__ float bf2f(unsigned short h) {
    unsigned int u = ((unsigned int)h) << 16;
    return __builtin_bit_cast(float, u);
}

// ---------------------------------------------------------------------------
// K0: weight prep (w1 -> wAt[tap][co][ci] bf16, w2 -> wC[co][ci] bf16),
//     zero BN stat accumulators (ws is re-poisoned to 0xAA every call).
// ---------------------------------------------------------------------------
__global__ __launch_bounds__(256) void k_prep(const float* __restrict__ w1,
                                              const float* __restrict__ w2,
                                              unsigned short* __restrict__ wAt,
                                              unsigned short* __restrict__ wC,
                                              float* __restrict__ stats /*1152*/) {
    int i = blockIdx.x * 256 + threadIdx.x;
    if (i < 82944) {                      // 9*96*96
        int tap = i / 9216;
        int r = i % 9216;
        int co = r / 96, ci = r % 96;
        wAt[i] = f2bf(w1[(co * 96 + ci) * 9 + tap]);
    } else if (i < 92160) {
        int j = i - 82944;
        wC[j] = f2bf(w2[j]);
    } else if (i < 93312) {
        stats[i - 92160] = 0.0f;
    }
}

// ---------------------------------------------------------------------------
// K1: rotated projection -> feat (v,b,y48,x48,c) bf16, c fastest.
// iy == y exactly; bilinear in (x,z), mean over 48 z. Incremental ix/iz.
// ---------------------------------------------------------------------------
__global__ __launch_bounds__(256) void k_feat(const float* __restrict__ tokens,
                                              const float* __restrict__ angles,
                                              unsigned short* __restrict__ feat) {
    int idx = blockIdx.x * 256 + threadIdx.x;
    int c = idx % Cn;
    int r = idx / Cn;
    int x = r % Wn; r /= Wn;
    int y = r % Hn; r /= Hn;
    int b = r & 1;
    int v = r >> 1;

    float th = angles[v];
    float ct = cosf(th), st = sinf(th);
    float X = (x + 0.5f) * (2.0f / 48.0f) - 1.0f;
    float Zc0 = 0.5f * (2.0f / 48.0f) - 1.0f;
    // ix = 24*gx + 23.5 ; per z-step: gx += st*(2/48) -> ix += st
    float ix = 24.0f * (ct * X + st * Zc0) + 23.5f;
    float iz = 24.0f * (-st * X + ct * Zc0) + 23.5f;

    const float* tb = tokens + (size_t)b * (Dn * Hn * Wn) * Cn + c;
    int yoff = y * Wn;

    float acc = 0.0f;
    for (int z = 0; z < Dn; ++z) {
        float x0f = floorf(ix), z0f = floorf(iz);
        float tx = ix - x0f, tz = iz - z0f;
        int x0 = (int)x0f, z0 = (int)z0f;
        float wx[2] = {1.0f - tx, tx};
        float wz[2] = {1.0f - tz, tz};
#pragma unroll
        for (int dz = 0; dz < 2; ++dz) {
            int zc = z0 + dz;
            bool zin = (zc >= 0) && (zc < Dn);
            int zi = min(max(zc, 0), Dn - 1);
#pragma unroll
            for (int dx = 0; dx < 2; ++dx) {
                int xc = x0 + dx;
                bool xin = (xc >= 0) && (xc < Wn);
                int xi = min(max(xc, 0), Wn - 1);
                float w = wx[dx] * wz[dz] * ((zin && xin) ? 1.0f : 0.0f);
                acc += w * tb[(size_t)((zi * Hn + y) * Wn + xi) * Cn];
            }
        }
        ix += st;
        iz += ct;
    }
    (void)yoff;
    feat[idx] = f2bf(acc * (1.0f / 48.0f));
}

// ---------------------------------------------------------------------------
// K2: bilinear resize 48x48 -> 96x96, bf16 in/out, (vb,y,x,c) c fastest.
// ---------------------------------------------------------------------------
__global__ __launch_bounds__(256) void k_resize(const unsigned short* __restrict__ feat,
                                                unsigned short* __restrict__ rz) {
    int idx = blockIdx.x * 256 + threadIdx.x;
    int c = idx % Cn;
    int r = idx / Cn;
    int x = r % TWn; r /= TWn;
    int y = r % THn;
    int vb = r / THn;

    float sy = fmaxf(0.5f * (y + 0.5f) - 0.5f, 0.0f);
    int y0 = min((int)sy, Hn - 1);
    int y1 = min(y0 + 1, Hn - 1);
    float ty = sy - (float)y0;
    float sx = fmaxf(0.5f * (x + 0.5f) - 0.5f, 0.0f);
    int x0 = min((int)sx, Wn - 1);
    int x1 = min(x0 + 1, Wn - 1);
    float tx = sx - (float)x0;

    const unsigned short* fb = feat + (size_t)vb * (Hn * Wn * Cn) + c;
    float f00 = bf2f(fb[(size_t)(y0 * Wn + x0) * Cn]);
    float f01 = bf2f(fb[(size_t)(y0 * Wn + x1) * Cn]);
    float f10 = bf2f(fb[(size_t)(y1 * Wn + x0) * Cn]);
    float f11 = bf2f(fb[(size_t)(y1 * Wn + x1) * Cn]);
    float val = (1.0f - ty) * ((1.0f - tx) * f00 + tx * f01)
              +          ty * ((1.0f - tx) * f10 + tx * f11);
    rz[idx] = f2bf(val);
}

// ---------------------------------------------------------------------------
// K3: conv1 3x3 SAME as implicit GEMM with bf16 MFMA 16x16x32.
// Block: 64 spatial (flattened n = vb*9216 + y*96 + x), full co=96.
// 4 waves x (N=16, M=96 -> 6 acc tiles). K = 9 taps x 96 ci (3 chunks of 32).
// LDS tile [4 rows][98 xx][ci 32 pad 40] bf16. Fused BN-stat atomics.
// Output co1[n][co] bf16, co fastest.
// ---------------------------------------------------------------------------
__global__ __launch_bounds__(256) void k_conv1(const unsigned short* __restrict__ rz,
                                               const unsigned short* __restrict__ wAt,
                                               unsigned short* __restrict__ co1,
                                               float* __restrict__ ssum,
                                               float* __restrict__ ssq) {
    __shared__ unsigned short tile[4 * 98 * 40];

    int blk = blockIdx.x;
    int n0 = blk * 64;                 // global spatial
    int vb = n0 / 9216;
    int nl0 = n0 - vb * 9216;
    int y0 = nl0 / 96;                 // first output row in block

    int t = threadIdx.x;
    int wv = t >> 6;
    int l = t & 63;
    int l15 = l & 15, q = l >> 4;

    int n_lane = nl0 + wv * 16 + l15;  // local spatial for B frag / store
    int yl = n_lane / 96;
    int xl = n_lane - yl * 96;
    int rowb = yl - y0;                // 0 or 1

    const unsigned short* rbase = rz + (size_t)vb * 9216 * 96;

    f4v acc[6];
#pragma unroll
    for (int mt = 0; mt < 6; ++mt) acc[mt] = (f4v){0.f, 0.f, 0.f, 0.f};

    for (int cc = 0; cc < 96; cc += 32) {
        __syncthreads();
        // stage rows y0-1..y0+2, xx 0..97 (x = xx-1), ci cc..cc+31 (zero halo)
        for (int e = t; e < 1568; e += 256) {
            int ci8 = (e & 3) * 8;
            int rx = e >> 2;           // 0..391
            int xx = rx % 98;
            int row = rx / 98;
            int yr = y0 - 1 + row;
            int xp = xx - 1;
            uint4 val = {0u, 0u, 0u, 0u};
            if (yr >= 0 && yr < 96 && xp >= 0 && xp < 96)
                val = *(const uint4*)(rbase + ((size_t)(yr * 96 + xp) * 96 + cc + ci8));
            *(uint4*)(&tile[(row * 98 + xx) * 40 + ci8]) = val;
        }
        __syncthreads();

#pragma unroll
        for (int tap = 0; tap < 9; ++tap) {
            int dy = tap / 3, dx = tap % 3;
            int row = rowb + dy;       // tile row of (yl + dy - 1)
            int xx = xl + dx;          // tile xx of (xl + dx - 1)
            s8v bfr = *(const s8v*)(&tile[(row * 98 + xx) * 40 + q * 8]);
            const unsigned short* ab = wAt + tap * 9216 + l15 * 96 + cc + q * 8;
#pragma unroll
            for (int mt = 0; mt < 6; ++mt) {
                s8v afr = *(const s8v*)(ab + mt * 1536);
                acc[mt] = __builtin_amdgcn_mfma_f32_16x16x32_bf16(afr, bfr, acc[mt], 0, 0, 0);
            }
        }
    }

    // epilogue: BN partial stats (reduce over 16 n-lanes) + bf16 store
    int vv = vb >> 1;
#pragma unroll
    for (int mt = 0; mt < 6; ++mt) {
        float s0 = acc[mt][0], s1 = acc[mt][1], s2 = acc[mt][2], s3 = acc[mt][3];
        float q0 = s0 * s0, q1 = s1 * s1, q2 = s2 * s2, q3 = s3 * s3;
#pragma unroll
        for (int off = 1; off < 16; off <<= 1) {
            s0 += __shfl_xor(s0, off); s1 += __shfl_xor(s1, off);
            s2 += __shfl_xor(s2, off); s3 += __shfl_xor(s3, off);
            q0 += __shfl_xor(q0, off); q1 += __shfl_xor(q1, off);
            q2 += __shfl_xor(q2, off); q3 += __shfl_xor(q3, off);
        }
        int co0 = mt * 16 + q * 4;     // D: row(m)=q*4+reg, col(n)=l15
        if (l15 == 0) {
            atomicAdd(&ssum[vv * 96 + co0 + 0], s0);
            atomicAdd(&ssum[vv * 96 + co0 + 1], s1);
            atomicAdd(&ssum[vv * 96 + co0 + 2], s2);
            atomicAdd(&ssum[vv * 96 + co0 + 3], s3);
            atomicAdd(&ssq[vv * 96 + co0 + 0], q0);
            atomicAdd(&ssq[vv * 96 + co0 + 1], q1);
            atomicAdd(&ssq[vv * 96 + co0 + 2], q2);
            atomicAdd(&ssq[vv * 96 + co0 + 3], q3);
        }
        ushort4 pk;
        pk.x = f2bf(acc[mt][0]); pk.y = f2bf(acc[mt][1]);
        pk.z = f2bf(acc[mt][2]); pk.w = f2bf(acc[mt][3]);
        *(ushort4*)(&co1[((size_t)(n0 + wv * 16 + l15)) * 96 + co0]) = pk;
    }
}

// ---------------------------------------------------------------------------
// K4: finalize BN -> per (v,c) scale/shift
// ---------------------------------------------------------------------------
__global__ __launch_bounds__(256) void k_musigma(const float* __restrict__ ssum,
                                                 const float* __restrict__ ssq,
                                                 const float* __restrict__ gamma,
                                                 const float* __restrict__ beta,
                                                 float* __restrict__ scale,
                                                 float* __restrict__ shift) {
    int i = blockIdx.x * 256 + threadIdx.x;
    if (i < Vn * Cn) {
        const float invN = 1.0f / (float)(Bn * THn * TWn);
        float mu = ssum[i] * invN;
        float var = ssq[i] * invN - mu * mu;
        float rstd = rsqrtf(fmaxf(var, 0.0f) + EPSf);
        int c = i % Cn;
        float sc = rstd * gamma[c];
        scale[i] = sc;
        shift[i] = beta[c] - mu * sc;
    }
}

// ---------------------------------------------------------------------------
// K5: fused BN + exact GELU + conv2 (1x1, MFMA) + bias + transpose to
//     out (b,v,co,y,x) fp32. Block: 64 spatial x 96 co, K=96.
// ---------------------------------------------------------------------------
__global__ __launch_bounds__(256) void k_conv2(const unsigned short* __restrict__ co1,
                                               const unsigned short* __restrict__ wC,
                                               const float* __restrict__ scale,
                                               const float* __restrict__ shift,
                                               const float* __restrict__ b2,
                                               float* __restrict__ out) {
    __shared__ unsigned short tile[64 * 104];
    __shared__ float sscale[96], sshift[96];

    int blk = blockIdx.x;
    int n0 = blk * 64;
    int vb = n0 / 9216;
    int v = vb >> 1, b = vb & 1;

    int t = threadIdx.x;
    int wv = t >> 6;
    int l = t & 63;
    int l15 = l & 15, q = l >> 4;

    if (t < 96) {
        sscale[t] = scale[v * 96 + t];
        sshift[t] = shift[v * 96 + t];
    }
    __syncthreads();

    // stage: load 8 bf16, BN + GELU, repack bf16 into LDS [n][ci pad 104]
    for (int e = t; e < 768; e += 256) {
        int ci8 = (e % 12) * 8;
        int n = e / 12;
        uint4 raw = *(const uint4*)(co1 + ((size_t)(n0 + n)) * 96 + ci8);
        unsigned int w[4] = {raw.x, raw.y, raw.z, raw.w};
        unsigned short o[8];
#pragma unroll
        for (int j = 0; j < 8; ++j) {
            unsigned short h = (unsigned short)((w[j >> 1] >> ((j & 1) * 16)) & 0xFFFFu);
            float xv = bf2f(h);
            float yv = xv * sscale[ci8 + j] + sshift[ci8 + j];
            float g = 0.5f * yv * (1.0f + erff(yv * 0.70710678118654752f));
            o[j] = f2bf(g);
        }
        uint4 pk;
        pk.x = (unsigned int)o[0] | ((unsigned int)o[1] << 16);
        pk.y = (unsigned int)o[2] | ((unsigned int)o[3] << 16);
        pk.z = (unsigned int)o[4] | ((unsigned int)o[5] << 16);
        pk.w = (unsigned int)o[6] | ((unsigned int)o[7] << 16);
        *(uint4*)(&tile[n * 104 + ci8]) = pk;
    }
    __syncthreads();

    f4v acc[6];
#pragma unroll
    for (int mt = 0; mt < 6; ++mt) acc[mt] = (f4v){0.f, 0.f, 0.f, 0.f};

    int nt = wv * 16 + l15;            // tile-local n
#pragma unroll
    for (int ks = 0; ks < 3; ++ks) {
        s8v bfr = *(const s8v*)(&tile[nt * 104 + ks * 32 + q * 8]);
        const unsigned short* ab = wC + l15 * 96 + ks * 32 + q * 8;
#pragma unroll
        for (int mt = 0; mt < 6; ++mt) {
            s8v afr = *(const s8v*)(ab + mt * 1536);
            acc[mt] = __builtin_amdgcn_mfma_f32_16x16x32_bf16(afr, bfr, acc[mt], 0, 0, 0);
        }
    }

    int nl = n0 - vb * 9216 + nt;      // local spatial in (y,x)
    size_t obase = ((size_t)(b * Vn + v) * Cn) * 9216;
#pragma unroll
    for (int mt = 0; mt < 6; ++mt) {
        int co0 = mt * 16 + q * 4;
#pragma unroll
        for (int reg = 0; reg < 4; ++reg) {
            int co = co0 + reg;
            out[obase + (size_t)co * 9216 + nl] = acc[mt][reg] + b2[co];
        }
    }
}

// ---------------------------------------------------------------------------
extern "C" void kernel_launch(void* const* d_in, const int* in_sizes, int n_in,
                              void* d_out, int out_size, void* d_ws, size_t ws_size,
                              hipStream_t stream) {
    const float* tokens = (const float*)d_in[0];
    const float* angles = (const float*)d_in[1];
    const float* w1     = (const float*)d_in[2];
    const float* gamma  = (const float*)d_in[3];
    const float* beta   = (const float*)d_in[4];
    const float* w2     = (const float*)d_in[5];
    const float* b2     = (const float*)d_in[6];
    float* out = (float*)d_out;

    // workspace layout (bytes)
    char* ws = (char*)d_ws;
    unsigned short* feat = (unsigned short*)(ws);                 //  5,308,416
    unsigned short* rz   = (unsigned short*)(ws + 5308416);       // 21,233,664
    unsigned short* co1  = (unsigned short*)(ws + 26542080);      // 21,233,664
    unsigned short* wAt  = (unsigned short*)(ws + 47775744);      //    165,888
    unsigned short* wC   = (unsigned short*)(ws + 47941632);      //     18,432
    float* ssum  = (float*)(ws + 47960064);                       //      2,304
    float* ssq   = ssum + 576;
    float* scale = (float*)(ws + 47964672);
    float* shift = scale + 576;

    k_prep<<<365, 256, 0, stream>>>(w1, w2, wAt, wC, ssum);
    k_feat<<<10368, 256, 0, stream>>>(tokens, angles, feat);
    k_resize<<<41472, 256, 0, stream>>>(feat, rz);
    k_conv1<<<1728, 256, 0, stream>>>(rz, wAt, co1, ssum, ssq);
    k_musigma<<<3, 256, 0, stream>>>(ssum, ssq, gamma, beta, scale, shift);
    k_conv2<<<1728, 256, 0, stream>>>(co1, wC, scale, shift, b2, out);
}

// Round 3
// 502.668 us; speedup vs baseline: 1.7895x; 1.3147x over previous
//
#include <hip/hip_runtime.h>
#include <math.h>

// Problem constants
#define Bn 2
#define Vn 6
#define Cn 96
#define Dn 48
#define Hn 48
#define Wn 48
#define THn 96
#define TWn 96
#define EPSf 1e-5f

typedef __attribute__((ext_vector_type(8))) short s8v;   // 8 bf16 (4 VGPRs)
typedef __attribute__((ext_vector_type(4))) float f4v;   // MFMA acc

__device__ __forceinline__ unsigned short f2bf(float f) {
    unsigned int u = __builtin_bit_cast(unsigned int, f);
    u += 0x7FFFu + ((u >> 16) & 1u);          // RNE
    return (unsigned short)(u >> 16);
}
__device__ __forceinline__ float bf2f(unsigned short h) {
    unsigned int u = ((unsigned int)h) << 16;
    return __builtin_bit_cast(float, u);
}

// ---------------------------------------------------------------------------
// K0: weight prep (w1 -> wAt[tap][co][ci] bf16, w2 -> wC[co][ci] bf16),
//     zero BN stat accumulators (ws is re-poisoned to 0xAA every call).
// ---------------------------------------------------------------------------
__global__ __launch_bounds__(256) void k_prep(const float* __restrict__ w1,
                                              const float* __restrict__ w2,
                                              unsigned short* __restrict__ wAt,
                                              unsigned short* __restrict__ wC,
                                              float* __restrict__ stats /*1152*/) {
    int i = blockIdx.x * 256 + threadIdx.x;
    if (i < 82944) {                      // 9*96*96
        int tap = i / 9216;
        int r = i % 9216;
        int co = r / 96, ci = r % 96;
        wAt[i] = f2bf(w1[(co * 96 + ci) * 9 + tap]);
    } else if (i < 92160) {
        int j = i - 82944;
        wC[j] = f2bf(w2[j]);
    } else if (i < 93312) {
        stats[i - 92160] = 0.0f;
    }
}

// ---------------------------------------------------------------------------
// K1: rotated projection -> feat (v,b,y48,x48,c) bf16, c fastest.
// iy == y exactly; bilinear in (x,z), mean over 48 z. 4 channels/thread
// (float4 tap loads), incremental ix/iz.
// ---------------------------------------------------------------------------
__global__ __launch_bounds__(256) void k_feat(const float* __restrict__ tokens,
                                              const float* __restrict__ angles,
                                              unsigned short* __restrict__ feat) {
    int idx = blockIdx.x * 256 + threadIdx.x;   // 663,552 total
    int c4 = (idx % 24) * 4;
    int r = idx / 24;
    int x = r % Wn; r /= Wn;
    int y = r % Hn; r /= Hn;
    int b = r & 1;
    int v = r >> 1;

    float th = angles[v];
    float ct = cosf(th), st = sinf(th);
    float X = (x + 0.5f) * (2.0f / 48.0f) - 1.0f;
    float Zc0 = 0.5f * (2.0f / 48.0f) - 1.0f;
    float ix = 24.0f * (ct * X + st * Zc0) + 23.5f;
    float iz = 24.0f * (-st * X + ct * Zc0) + 23.5f;

    const float* tb = tokens + (size_t)b * (Dn * Hn * Wn) * Cn + c4;
    int ybase = y * Wn;

    float a0 = 0.f, a1 = 0.f, a2 = 0.f, a3 = 0.f;
    for (int z = 0; z < Dn; ++z) {
        float x0f = floorf(ix), z0f = floorf(iz);
        float tx = ix - x0f, tz = iz - z0f;
        int x0 = (int)x0f, z0 = (int)z0f;
        float wx[2] = {1.0f - tx, tx};
        float wz[2] = {1.0f - tz, tz};
#pragma unroll
        for (int dz = 0; dz < 2; ++dz) {
            int zc = z0 + dz;
            bool zin = (zc >= 0) && (zc < Dn);
            int zi = min(max(zc, 0), Dn - 1);
            int zoff = (zi * Hn + 0) * Wn;
#pragma unroll
            for (int dx = 0; dx < 2; ++dx) {
                int xc = x0 + dx;
                bool xin = (xc >= 0) && (xc < Wn);
                int xi = min(max(xc, 0), Wn - 1);
                float w = wx[dx] * wz[dz] * ((zin && xin) ? 1.0f : 0.0f);
                float4 t = *(const float4*)(tb + (size_t)(zoff + ybase + xi) * Cn);
                a0 += w * t.x; a1 += w * t.y; a2 += w * t.z; a3 += w * t.w;
            }
        }
        ix += st;
        iz += ct;
    }
    const float s = 1.0f / 48.0f;
    ushort4 pk;
    pk.x = f2bf(a0 * s); pk.y = f2bf(a1 * s);
    pk.z = f2bf(a2 * s); pk.w = f2bf(a3 * s);
    *(ushort4*)(&feat[(size_t)(idx / 24) * Cn + c4]) = pk;
}

// ---------------------------------------------------------------------------
// K2: bilinear resize 48x48 -> 96x96, bf16, (vb,y,x,c) c fastest. 8 ch/thread.
// ---------------------------------------------------------------------------
__global__ __launch_bounds__(256) void k_resize(const unsigned short* __restrict__ feat,
                                                unsigned short* __restrict__ rz) {
    int idx = blockIdx.x * 256 + threadIdx.x;   // 1,327,104 total
    int c8 = (idx % 12) * 8;
    int r = idx / 12;
    int x = r % TWn; r /= TWn;
    int y = r % THn;
    int vb = r / THn;

    float sy = fmaxf(0.5f * (y + 0.5f) - 0.5f, 0.0f);
    int y0 = min((int)sy, Hn - 1);
    int y1 = min(y0 + 1, Hn - 1);
    float ty = sy - (float)y0;
    float sx = fmaxf(0.5f * (x + 0.5f) - 0.5f, 0.0f);
    int x0 = min((int)sx, Wn - 1);
    int x1 = min(x0 + 1, Wn - 1);
    float tx = sx - (float)x0;

    const unsigned short* fb = feat + (size_t)vb * (Hn * Wn * Cn) + c8;
    uint4 r00 = *(const uint4*)(fb + (size_t)(y0 * Wn + x0) * Cn);
    uint4 r01 = *(const uint4*)(fb + (size_t)(y0 * Wn + x1) * Cn);
    uint4 r10 = *(const uint4*)(fb + (size_t)(y1 * Wn + x0) * Cn);
    uint4 r11 = *(const uint4*)(fb + (size_t)(y1 * Wn + x1) * Cn);
    const unsigned int* p00 = (const unsigned int*)&r00;
    const unsigned int* p01 = (const unsigned int*)&r01;
    const unsigned int* p10 = (const unsigned int*)&r10;
    const unsigned int* p11 = (const unsigned int*)&r11;

    float w00 = (1.f - ty) * (1.f - tx), w01 = (1.f - ty) * tx;
    float w10 = ty * (1.f - tx),         w11 = ty * tx;

    unsigned short o[8];
#pragma unroll
    for (int j = 0; j < 8; ++j) {
        int wi = j >> 1, sh = (j & 1) * 16;
        float f00 = bf2f((unsigned short)((p00[wi] >> sh) & 0xFFFFu));
        float f01 = bf2f((unsigned short)((p01[wi] >> sh) & 0xFFFFu));
        float f10 = bf2f((unsigned short)((p10[wi] >> sh) & 0xFFFFu));
        float f11 = bf2f((unsigned short)((p11[wi] >> sh) & 0xFFFFu));
        o[j] = f2bf(w00 * f00 + w01 * f01 + w10 * f10 + w11 * f11);
    }
    uint4 pk;
    pk.x = (unsigned int)o[0] | ((unsigned int)o[1] << 16);
    pk.y = (unsigned int)o[2] | ((unsigned int)o[3] << 16);
    pk.z = (unsigned int)o[4] | ((unsigned int)o[5] << 16);
    pk.w = (unsigned int)o[6] | ((unsigned int)o[7] << 16);
    *(uint4*)(&rz[(size_t)(idx / 12) * Cn + c8]) = pk;
}

// ---------------------------------------------------------------------------
// K3: conv1 3x3 SAME, barrier-free implicit GEMM (bf16 MFMA 16x16x32).
// Wave = 32 spatial (2 n-tiles) x 96 co. B-frags loaded DIRECTLY from global
// (ci-contiguous 16B per lane; 4 q-lanes cover a 64B line; taps re-hit L1).
// Zero-pad via predicated loads. Fused BN-stat atomics.
// ---------------------------------------------------------------------------
__global__ __launch_bounds__(256) void k_conv1(const unsigned short* __restrict__ rz,
                                               const unsigned short* __restrict__ wAt,
                                               unsigned short* __restrict__ co1,
                                               float* __restrict__ ssum,
                                               float* __restrict__ ssq) {
    int blk = blockIdx.x;
    int n0 = blk * 128;                // 9216 % 128 == 0 -> single vb per block
    int vb = n0 / 9216;
    int nl0 = n0 - vb * 9216;

    int t = threadIdx.x;
    int wv = t >> 6;
    int l = t & 63;
    int l15 = l & 15, q = l >> 4;

    // two n-tiles per wave
    int nA = nl0 + wv * 32 + l15;
    int nB = nA + 16;
    int yA = nA / 96, xA = nA - yA * 96;
    int yB = nB / 96, xB = nB - yB * 96;

    const unsigned short* base = rz + (size_t)vb * 9216 * 96;

    f4v acc[2][6];
#pragma unroll
    for (int i = 0; i < 2; ++i)
#pragma unroll
        for (int mt = 0; mt < 6; ++mt) acc[i][mt] = (f4v){0.f, 0.f, 0.f, 0.f};

#pragma unroll
    for (int cc = 0; cc < 96; cc += 32) {
#pragma unroll
        for (int tap = 0; tap < 9; ++tap) {
            int dy = tap / 3 - 1, dx = tap % 3 - 1;
            int yyA = yA + dy, xxA = xA + dx;
            int yyB = yB + dy, xxB = xB + dx;
            s8v b0 = (s8v){0,0,0,0,0,0,0,0};
            s8v b1 = (s8v){0,0,0,0,0,0,0,0};
            if ((unsigned)yyA < 96u && (unsigned)xxA < 96u)
                b0 = *(const s8v*)(base + (size_t)(yyA * 96 + xxA) * 96 + cc + q * 8);
            if ((unsigned)yyB < 96u && (unsigned)xxB < 96u)
                b1 = *(const s8v*)(base + (size_t)(yyB * 96 + xxB) * 96 + cc + q * 8);
            const unsigned short* ap = wAt + tap * 9216 + l15 * 96 + cc + q * 8;
#pragma unroll
            for (int mt = 0; mt < 6; ++mt) {
                s8v a = *(const s8v*)(ap + mt * 1536);
                acc[0][mt] = __builtin_amdgcn_mfma_f32_16x16x32_bf16(a, b0, acc[0][mt], 0, 0, 0);
                acc[1][mt] = __builtin_amdgcn_mfma_f32_16x16x32_bf16(a, b1, acc[1][mt], 0, 0, 0);
            }
        }
    }

    // epilogue: BN partial stats + bf16 store, layout co1[n][co]
    int vv = vb >> 1;
#pragma unroll
    for (int i = 0; i < 2; ++i) {
        int n = n0 + wv * 32 + i * 16 + l15;
#pragma unroll
        for (int mt = 0; mt < 6; ++mt) {
            float s0 = acc[i][mt][0], s1 = acc[i][mt][1];
            float s2 = acc[i][mt][2], s3 = acc[i][mt][3];
            float q0 = s0 * s0, q1 = s1 * s1, q2 = s2 * s2, q3 = s3 * s3;
#pragma unroll
            for (int off = 1; off < 16; off <<= 1) {
                s0 += __shfl_xor(s0, off); s1 += __shfl_xor(s1, off);
                s2 += __shfl_xor(s2, off); s3 += __shfl_xor(s3, off);
                q0 += __shfl_xor(q0, off); q1 += __shfl_xor(q1, off);
                q2 += __shfl_xor(q2, off); q3 += __shfl_xor(q3, off);
            }
            int co0 = mt * 16 + q * 4;     // D: row(m)=q*4+reg, col(n)=l15
            if (l15 == 0) {
                atomicAdd(&ssum[vv * 96 + co0 + 0], s0);
                atomicAdd(&ssum[vv * 96 + co0 + 1], s1);
                atomicAdd(&ssum[vv * 96 + co0 + 2], s2);
                atomicAdd(&ssum[vv * 96 + co0 + 3], s3);
                atomicAdd(&ssq[vv * 96 + co0 + 0], q0);
                atomicAdd(&ssq[vv * 96 + co0 + 1], q1);
                atomicAdd(&ssq[vv * 96 + co0 + 2], q2);
                atomicAdd(&ssq[vv * 96 + co0 + 3], q3);
            }
            ushort4 pk;
            pk.x = f2bf(acc[i][mt][0]); pk.y = f2bf(acc[i][mt][1]);
            pk.z = f2bf(acc[i][mt][2]); pk.w = f2bf(acc[i][mt][3]);
            *(ushort4*)(&co1[(size_t)n * 96 + co0]) = pk;
        }
    }
}

// ---------------------------------------------------------------------------
// K4: finalize BN -> per (v,c) scale/shift
// ---------------------------------------------------------------------------
__global__ __launch_bounds__(256) void k_musigma(const float* __restrict__ ssum,
                                                 const float* __restrict__ ssq,
                                                 const float* __restrict__ gamma,
                                                 const float* __restrict__ beta,
                                                 float* __restrict__ scale,
                                                 float* __restrict__ shift) {
    int i = blockIdx.x * 256 + threadIdx.x;
    if (i < Vn * Cn) {
        const float invN = 1.0f / (float)(Bn * THn * TWn);
        float mu = ssum[i] * invN;
        float var = ssq[i] * invN - mu * mu;
        float rstd = rsqrtf(fmaxf(var, 0.0f) + EPSf);
        int c = i % Cn;
        float sc = rstd * gamma[c];
        scale[i] = sc;
        shift[i] = beta[c] - mu * sc;
    }
}

// ---------------------------------------------------------------------------
// K5: fused BN + exact GELU (in-register) + conv2 1x1 MFMA + bias +
//     transpose to out (b,v,co,y,x) fp32. Wave = 32 n x 96 co. No act LDS.
// ---------------------------------------------------------------------------
__global__ __launch_bounds__(256) void k_conv2(const unsigned short* __restrict__ co1,
                                               const unsigned short* __restrict__ wC,
                                               const float* __restrict__ scale,
                                               const float* __restrict__ shift,
                                               const float* __restrict__ b2,
                                               float* __restrict__ out) {
    __shared__ float sscale[96], sshift[96];

    int blk = blockIdx.x;
    int n0 = blk * 128;
    int vb = n0 / 9216;
    int v = vb >> 1, b = vb & 1;

    int t = threadIdx.x;
    int wv = t >> 6;
    int l = t & 63;
    int l15 = l & 15, q = l >> 4;

    if (t < 96) {
        sscale[t] = scale[v * 96 + t];
        sshift[t] = shift[v * 96 + t];
    }
    __syncthreads();

    f4v acc[2][6];
#pragma unroll
    for (int i = 0; i < 2; ++i)
#pragma unroll
        for (int mt = 0; mt < 6; ++mt) acc[i][mt] = (f4v){0.f, 0.f, 0.f, 0.f};

    int nA = n0 + wv * 32 + l15;

#pragma unroll
    for (int ks = 0; ks < 3; ++ks) {
        int ci0 = ks * 32 + q * 8;
        float sc[8], sh[8];
#pragma unroll
        for (int j = 0; j < 8; ++j) { sc[j] = sscale[ci0 + j]; sh[j] = sshift[ci0 + j]; }
        s8v bf[2];
#pragma unroll
        for (int i = 0; i < 2; ++i) {
            uint4 raw = *(const uint4*)(co1 + (size_t)(nA + i * 16) * 96 + ci0);
            const unsigned int* pw = (const unsigned int*)&raw;
            unsigned short o[8];
#pragma unroll
            for (int j = 0; j < 8; ++j) {
                unsigned short h = (unsigned short)((pw[j >> 1] >> ((j & 1) * 16)) & 0xFFFFu);
                float yv = bf2f(h) * sc[j] + sh[j];
                float g = 0.5f * yv * (1.0f + erff(yv * 0.70710678118654752f));
                o[j] = f2bf(g);
            }
            unsigned int w0 = (unsigned int)o[0] | ((unsigned int)o[1] << 16);
            unsigned int w1 = (unsigned int)o[2] | ((unsigned int)o[3] << 16);
            unsigned int w2_ = (unsigned int)o[4] | ((unsigned int)o[5] << 16);
            unsigned int w3 = (unsigned int)o[6] | ((unsigned int)o[7] << 16);
            uint4 pk = {w0, w1, w2_, w3};
            bf[i] = __builtin_bit_cast(s8v, pk);
        }
        const unsigned short* ap = wC + l15 * 96 + ci0;
#pragma unroll
        for (int mt = 0; mt < 6; ++mt) {
            s8v a = *(const s8v*)(ap + mt * 1536);
            acc[0][mt] = __builtin_amdgcn_mfma_f32_16x16x32_bf16(a, bf[0], acc[0][mt], 0, 0, 0);
            acc[1][mt] = __builtin_amdgcn_mfma_f32_16x16x32_bf16(a, bf[1], acc[1][mt], 0, 0, 0);
        }
    }

    int nl0 = n0 - vb * 9216;
    size_t obase = ((size_t)(b * Vn + v) * Cn) * 9216;
#pragma unroll
    for (int i = 0; i < 2; ++i) {
        int nl = nl0 + wv * 32 + i * 16 + l15;
#pragma unroll
        for (int mt = 0; mt < 6; ++mt) {
            int co0 = mt * 16 + q * 4;
#pragma unroll
            for (int reg = 0; reg < 4; ++reg) {
                int co = co0 + reg;
                out[obase + (size_t)co * 9216 + nl] = acc[i][mt][reg] + b2[co];
            }
        }
    }
}

// ---------------------------------------------------------------------------
extern "C" void kernel_launch(void* const* d_in, const int* in_sizes, int n_in,
                              void* d_out, int out_size, void* d_ws, size_t ws_size,
                              hipStream_t stream) {
    const float* tokens = (const float*)d_in[0];
    const float* angles = (const float*)d_in[1];
    const float* w1     = (const float*)d_in[2];
    const float* gamma  = (const float*)d_in[3];
    const float* beta   = (const float*)d_in[4];
    const float* w2     = (const float*)d_in[5];
    const float* b2     = (const float*)d_in[6];
    float* out = (float*)d_out;

    // workspace layout (bytes)
    char* ws = (char*)d_ws;
    unsigned short* feat = (unsigned short*)(ws);                 //  5,308,416
    unsigned short* rz   = (unsigned short*)(ws + 5308416);       // 21,233,664
    unsigned short* co1  = (unsigned short*)(ws + 26542080);      // 21,233,664
    unsigned short* wAt  = (unsigned short*)(ws + 47775744);      //    165,888
    unsigned short* wC   = (unsigned short*)(ws + 47941632);      //     18,432
    float* ssum  = (float*)(ws + 47960064);                       //      2,304
    float* ssq   = ssum + 576;
    float* scale = (float*)(ws + 47964672);
    float* shift = scale + 576;

    k_prep<<<365, 256, 0, stream>>>(w1, w2, wAt, wC, ssum);
    k_feat<<<2592, 256, 0, stream>>>(tokens, angles, feat);
    k_resize<<<5184, 256, 0, stream>>>(feat, rz);
    k_conv1<<<864, 256, 0, stream>>>(rz, wAt, co1, ssum, ssq);
    k_musigma<<<3, 256, 0, stream>>>(ssum, ssq, gamma, beta, scale, shift);
    k_conv2<<<864, 256, 0, stream>>>(co1, wC, scale, shift, b2, out);
}